// Round 2
// baseline (144.040 us; speedup 1.0000x reference)
//
#include <hip/hip_runtime.h>
#include <hip/hip_bf16.h>
#include <stdint.h>

#define NNODES 100000
#define DIN    256
#define DOUT   128
#define KNB    16

typedef __attribute__((ext_vector_type(8))) __bf16 bf16x8;
typedef __attribute__((ext_vector_type(4))) float  f32x4;
typedef __attribute__((ext_vector_type(8))) unsigned short u16x8;

// ---------------------------------------------------------------------------
// Kernel 0: Wt[c][k] = bf16(W[k][c])   (128 x 256 bf16 = 64 KB, L2-resident)
// ---------------------------------------------------------------------------
__global__ __launch_bounds__(256)
void gc_wt(const float* __restrict__ W, unsigned short* __restrict__ Wt)
{
    const int idx = blockIdx.x * 256 + threadIdx.x;   // 0 .. 32767
    const int k = idx >> 7;        // 0..255
    const int c = idx & 127;       // 0..127
    Wt[c * DIN + k] = __builtin_bit_cast(unsigned short, (__bf16)W[idx]);
}

// ---------------------------------------------------------------------------
// Kernel 1: h = relu(feats @ W + b) -> bf16.
// Block = 256 threads (4 waves). Tile = 64 rows x 128 cols; wave w: cols
// [32w,32w+32). B fragments from Wt via one 16B load each. A direct from
// global (16 rows x 128B contiguous segments per wave-load-pair).
// MFMA 16x16x32 bf16; D: col = lane&15, row = (lane>>4)*4 + r.
// ---------------------------------------------------------------------------
__global__ __launch_bounds__(256, 4)
void gc_linear_relu(const float* __restrict__ feats,
                    const unsigned short* __restrict__ Wt,
                    const float* __restrict__ bias,
                    unsigned short* __restrict__ h)
{
    const int lane = threadIdx.x & 63;
    const int wave = threadIdx.x >> 6;      // 0..3
    const int brow = blockIdx.x * 64;
    const int wcol = wave * 32;

    const int fr = lane & 15;               // A-row / B-col / D-col in tile
    const int kb = lane >> 4;               // 0..3 k-block

    // ---- B fragments: one dwordx4 each from Wt (bf16, k-contiguous) ----
    bf16x8 bfrag[2][8];
    #pragma unroll
    for (int ct = 0; ct < 2; ++ct) {
        const int col = wcol + ct * 16 + fr;
        const unsigned short* wp = Wt + col * DIN;
        #pragma unroll
        for (int ks = 0; ks < 8; ++ks) {
            const int k0 = ks * 32 + kb * 8;
            bfrag[ct][ks] = __builtin_bit_cast(bf16x8,
                *reinterpret_cast<const u16x8*>(wp + k0));
        }
    }

    f32x4 acc[4][2];
    #pragma unroll
    for (int rt = 0; rt < 4; ++rt)
        #pragma unroll
        for (int ct = 0; ct < 2; ++ct)
            acc[rt][ct] = (f32x4){0.f, 0.f, 0.f, 0.f};

    #pragma unroll
    for (int rt = 0; rt < 4; ++rt) {
        int row = brow + rt * 16 + fr;
        if (row >= NNODES) row = NNODES - 1;       // clamp loads; stores guarded
        const float* ap = feats + (size_t)row * DIN;
        #pragma unroll
        for (int ks = 0; ks < 8; ++ks) {
            const int k0 = ks * 32 + kb * 8;
            const float4 a0 = *reinterpret_cast<const float4*>(ap + k0);
            const float4 a1 = *reinterpret_cast<const float4*>(ap + k0 + 4);
            bf16x8 af;
            af[0] = (__bf16)a0.x; af[1] = (__bf16)a0.y;
            af[2] = (__bf16)a0.z; af[3] = (__bf16)a0.w;
            af[4] = (__bf16)a1.x; af[5] = (__bf16)a1.y;
            af[6] = (__bf16)a1.z; af[7] = (__bf16)a1.w;
            acc[rt][0] = __builtin_amdgcn_mfma_f32_16x16x32_bf16(af, bfrag[0][ks], acc[rt][0], 0, 0, 0);
            acc[rt][1] = __builtin_amdgcn_mfma_f32_16x16x32_bf16(af, bfrag[1][ks], acc[rt][1], 0, 0, 0);
        }
    }

    // ---- epilogue: +bias, relu, bf16 store ----
    float bv[2];
    bv[0] = bias[wcol + fr];
    bv[1] = bias[wcol + 16 + fr];
    #pragma unroll
    for (int rt = 0; rt < 4; ++rt) {
        #pragma unroll
        for (int ct = 0; ct < 2; ++ct) {
            const int col = wcol + ct * 16 + fr;
            #pragma unroll
            for (int r = 0; r < 4; ++r) {
                const int grow = brow + rt * 16 + kb * 4 + r;
                if (grow < NNODES) {
                    float v = fmaxf(acc[rt][ct][r] + bv[ct], 0.f);
                    h[(size_t)grow * DOUT + col] =
                        __builtin_bit_cast(unsigned short, (__bf16)v);
                }
            }
        }
    }
}

// ---------------------------------------------------------------------------
// Kernel 2: out[i][:] = mean_k h[edge[i][k]][:]
// 16 nodes / 256-thread block; 16 lanes per node, 16B (8 bf16) per lane.
// Each 16-lane group reads one full 256B h-row per neighbor.
// ---------------------------------------------------------------------------
__global__ __launch_bounds__(256)
void gc_gather_mean(const int* __restrict__ edge,
                    const unsigned short* __restrict__ h,
                    float* __restrict__ out)
{
    const int t    = threadIdx.x;
    const int grp  = t >> 4;          // 0..15 node within block
    const int c4   = t & 15;          // 16B chunk within row
    const int node = blockIdx.x * 16 + grp;
    if (node >= NNODES) return;

    const int* ep = edge + node * KNB;
    float s[8];
    #pragma unroll
    for (int j = 0; j < 8; ++j) s[j] = 0.f;

    #pragma unroll
    for (int k = 0; k < KNB; ++k) {
        const int nb = ep[k];
        const u16x8 v = *reinterpret_cast<const u16x8*>(h + (size_t)nb * DOUT + c4 * 8);
        const uint32_t* pw = reinterpret_cast<const uint32_t*>(&v);
        #pragma unroll
        for (int p = 0; p < 4; ++p) {
            union { uint32_t u; float f; } lo, hi;
            lo.u = pw[p] << 16;
            hi.u = pw[p] & 0xFFFF0000u;
            s[2 * p]     += lo.f;
            s[2 * p + 1] += hi.f;
        }
    }

    float* op = out + (size_t)node * DOUT + c4 * 8;
    float4 o0 = make_float4(s[0], s[1], s[2], s[3]);
    float4 o1 = make_float4(s[4], s[5], s[6], s[7]);
    o0.x *= 0.0625f; o0.y *= 0.0625f; o0.z *= 0.0625f; o0.w *= 0.0625f;
    o1.x *= 0.0625f; o1.y *= 0.0625f; o1.z *= 0.0625f; o1.w *= 0.0625f;
    *reinterpret_cast<float4*>(op)     = o0;
    *reinterpret_cast<float4*>(op + 4) = o1;
}

extern "C" void kernel_launch(void* const* d_in, const int* in_sizes, int n_in,
                              void* d_out, int out_size, void* d_ws, size_t ws_size,
                              hipStream_t stream)
{
    const float* feats = (const float*)d_in[0];
    const int*   edge  = (const int*)d_in[1];
    const float* W     = (const float*)d_in[2];
    const float* bias  = (const float*)d_in[3];
    float* out = (float*)d_out;

    const size_t h_bytes  = (size_t)NNODES * DOUT * sizeof(unsigned short); // 25.6 MB
    const size_t wt_bytes = (size_t)DIN * DOUT * sizeof(unsigned short);    // 64 KB

    unsigned short* h = (unsigned short*)d_ws;
    // Wt goes in ws if it fits; else stash it in d_out (gather fully
    // overwrites d_out afterwards, same stream => deterministic).
    unsigned short* Wt;
    if (ws_size >= h_bytes + wt_bytes)
        Wt = (unsigned short*)((char*)d_ws + h_bytes);
    else
        Wt = (unsigned short*)d_out;

    gc_wt<<<(DIN * DOUT) / 256, 256, 0, stream>>>(W, (unsigned short*)Wt);

    const int gemm_blocks = (NNODES + 63) / 64;     // 1563
    gc_linear_relu<<<gemm_blocks, 256, 0, stream>>>(feats, Wt, bias, h);

    const int gat_blocks = (NNODES + 15) / 16;      // 6250
    gc_gather_mean<<<gat_blocks, 256, 0, stream>>>(edge, h, out);
}

// Round 4
// 105.290 us; speedup vs baseline: 1.3680x; 1.3680x over previous
//
#include <hip/hip_runtime.h>
#include <hip/hip_bf16.h>
#include <stdint.h>

#define NNODES 100000
#define DIN    256
#define DOUT   128
#define KNB    16

typedef __attribute__((ext_vector_type(8))) __bf16 bf16x8;
typedef __attribute__((ext_vector_type(4))) float  f32x4;
typedef __attribute__((ext_vector_type(8))) unsigned short u16x8;

// ---------------------------------------------------------------------------
// Kernel 0: Wt[c][k] = bf16(W[k][c])  (128 x 256 bf16 = 64 KB, L2-resident)
// consecutive threads -> consecutive k -> coalesced Wt writes.
// ---------------------------------------------------------------------------
__global__ __launch_bounds__(256)
void gc_wt(const float* __restrict__ W, unsigned short* __restrict__ Wt)
{
    const int idx = blockIdx.x * 256 + threadIdx.x;   // 0 .. 32767
    const int c = idx >> 8;        // 0..127
    const int k = idx & 255;       // 0..255
    Wt[c * DIN + k] = __builtin_bit_cast(unsigned short, (__bf16)W[k * DOUT + c]);
}

// ---------------------------------------------------------------------------
// Kernel 1: h = relu(feats @ W + b) -> bf16.
// 256 thr (4 waves), tile 64 rows x 128 cols, K=256 in one shot.
// Stage: 16 nontemporal f32x4 loads ALL issued first (MLP), cvt -> bf16,
//        ds_write_b128 into As[64][256] with 16B-chunk XOR swizzle (^row&15).
// Compute: ds_read_b128 A-fragments (conflict-free via same swizzle),
//          mfma(bfrag, afrag) so D regs run along 4 consecutive h columns.
// Epilogue: +bias, relu, pack 4 bf16 -> one 8B store per (rt,ct).
// ---------------------------------------------------------------------------
__global__ __launch_bounds__(256, 2)
void gc_linear_relu(const float* __restrict__ feats,
                    const unsigned short* __restrict__ Wt,
                    const float* __restrict__ bias,
                    unsigned short* __restrict__ h)
{
    __shared__ unsigned short As[64 * 256];   // 32 KB bf16, swizzled chunks

    const int t    = threadIdx.x;
    const int lane = t & 63;
    const int wave = t >> 6;                  // 0..3
    const int brow = blockIdx.x * 64;
    const int wcol = wave * 32;
    const int fr   = lane & 15;
    const int kb   = lane >> 4;               // 0..3

    // ---- stage A: issue all 16 global loads first, then cvt+write ----
    f32x4 sa[8], sb[8];
    int   srow[8], schk[8];
    #pragma unroll
    for (int i = 0; i < 8; ++i) {
        const int id = i * 256 + t;           // 16B-chunk id, 0..2047
        const int r  = id >> 5;               // 0..63
        const int c  = id & 31;               // chunk within row
        int gr = brow + r; if (gr >= NNODES) gr = NNODES - 1;
        const float* ap = feats + (size_t)gr * DIN + c * 8;
        sa[i] = __builtin_nontemporal_load(reinterpret_cast<const f32x4*>(ap));
        sb[i] = __builtin_nontemporal_load(reinterpret_cast<const f32x4*>(ap + 4));
        srow[i] = r;
        schk[i] = c ^ (r & 15);               // XOR swizzle
    }

    // ---- B fragments from Wt: 16 x 16B L2 loads, independent of staging ----
    bf16x8 bfrag[2][8];
    #pragma unroll
    for (int ct = 0; ct < 2; ++ct) {
        const unsigned short* wp = Wt + (wcol + ct * 16 + fr) * DIN;
        #pragma unroll
        for (int ks = 0; ks < 8; ++ks)
            bfrag[ct][ks] = __builtin_bit_cast(bf16x8,
                *reinterpret_cast<const u16x8*>(wp + ks * 32 + kb * 8));
    }

    #pragma unroll
    for (int i = 0; i < 8; ++i) {
        bf16x8 v;
        v[0] = (__bf16)sa[i][0]; v[1] = (__bf16)sa[i][1];
        v[2] = (__bf16)sa[i][2]; v[3] = (__bf16)sa[i][3];
        v[4] = (__bf16)sb[i][0]; v[5] = (__bf16)sb[i][1];
        v[6] = (__bf16)sb[i][2]; v[7] = (__bf16)sb[i][3];
        *reinterpret_cast<bf16x8*>(&As[srow[i] * 256 + schk[i] * 8]) = v;
    }
    __syncthreads();

    // ---- MFMA ----
    f32x4 acc[4][2];
    #pragma unroll
    for (int rt = 0; rt < 4; ++rt)
        #pragma unroll
        for (int ct = 0; ct < 2; ++ct)
            acc[rt][ct] = (f32x4){0.f, 0.f, 0.f, 0.f};

    #pragma unroll
    for (int rt = 0; rt < 4; ++rt) {
        const int row = rt * 16 + fr;
        #pragma unroll
        for (int ks = 0; ks < 8; ++ks) {
            const int chunk = (ks * 4 + kb) ^ fr;   // row&15 == fr
            const bf16x8 af = *reinterpret_cast<const bf16x8*>(&As[row * 256 + chunk * 8]);
            // swapped operands: D col(lane&15)=feats row, D rows = W cols
            acc[rt][0] = __builtin_amdgcn_mfma_f32_16x16x32_bf16(bfrag[0][ks], af, acc[rt][0], 0, 0, 0);
            acc[rt][1] = __builtin_amdgcn_mfma_f32_16x16x32_bf16(bfrag[1][ks], af, acc[rt][1], 0, 0, 0);
        }
    }

    // ---- epilogue: h[brow+rt*16+fr][wcol+ct*16+kb*4 + r], r=0..3 ----
    #pragma unroll
    for (int rt = 0; rt < 4; ++rt) {
        const int grow = brow + rt * 16 + fr;
        if (grow < NNODES) {
            #pragma unroll
            for (int ct = 0; ct < 2; ++ct) {
                const int colb = wcol + ct * 16 + kb * 4;
                union { unsigned short us[4]; uint2 v; } o;
                o.us[0] = __builtin_bit_cast(unsigned short, (__bf16)fmaxf(acc[rt][ct][0] + bias[colb + 0], 0.f));
                o.us[1] = __builtin_bit_cast(unsigned short, (__bf16)fmaxf(acc[rt][ct][1] + bias[colb + 1], 0.f));
                o.us[2] = __builtin_bit_cast(unsigned short, (__bf16)fmaxf(acc[rt][ct][2] + bias[colb + 2], 0.f));
                o.us[3] = __builtin_bit_cast(unsigned short, (__bf16)fmaxf(acc[rt][ct][3] + bias[colb + 3], 0.f));
                *reinterpret_cast<uint2*>(h + (size_t)grow * DOUT + colb) = o.v;
            }
        }
    }
}

// ---------------------------------------------------------------------------
// Kernel 2: out[i][:] = mean_k h[edge[i][k]][:]
// 16 nodes / 256-thread block; 16 lanes per node, 16B per lane.
// edge loaded once per lane (lane c4 holds k=c4), broadcast via __shfl.
// Nontemporal out stores (never re-read; keep h hot in L2/L3).
// ---------------------------------------------------------------------------
__global__ __launch_bounds__(256)
void gc_gather_mean(const int* __restrict__ edge,
                    const unsigned short* __restrict__ h,
                    float* __restrict__ out)
{
    const int t    = threadIdx.x;
    const int grp  = t >> 4;          // node within block (0..15)
    const int c4   = t & 15;          // 16B chunk within row == k index
    const int node = blockIdx.x * 16 + grp;
    const int gbase = (t & 63) & 48;  // this lane's 16-lane group base in wave

    const int nb_mine = edge[node * KNB + c4];   // lane c4 holds neighbor k=c4

    float s[8];
    #pragma unroll
    for (int j = 0; j < 8; ++j) s[j] = 0.f;

    #pragma unroll
    for (int k = 0; k < KNB; ++k) {
        const int nb = __shfl(nb_mine, gbase | k);   // broadcast within group
        const u16x8 v = *reinterpret_cast<const u16x8*>(h + (size_t)nb * DOUT + c4 * 8);
        const uint32_t* pw = reinterpret_cast<const uint32_t*>(&v);
        #pragma unroll
        for (int p = 0; p < 4; ++p) {
            union { uint32_t u; float f; } lo, hi;
            lo.u = pw[p] << 16;
            hi.u = pw[p] & 0xFFFF0000u;
            s[2 * p]     += lo.f;
            s[2 * p + 1] += hi.f;
        }
    }

    float* op = out + (size_t)node * DOUT + c4 * 8;
    f32x4 o0 = {s[0] * 0.0625f, s[1] * 0.0625f, s[2] * 0.0625f, s[3] * 0.0625f};
    f32x4 o1 = {s[4] * 0.0625f, s[5] * 0.0625f, s[6] * 0.0625f, s[7] * 0.0625f};
    __builtin_nontemporal_store(o0, reinterpret_cast<f32x4*>(op));
    __builtin_nontemporal_store(o1, reinterpret_cast<f32x4*>(op + 4));
}

extern "C" void kernel_launch(void* const* d_in, const int* in_sizes, int n_in,
                              void* d_out, int out_size, void* d_ws, size_t ws_size,
                              hipStream_t stream)
{
    const float* feats = (const float*)d_in[0];
    const int*   edge  = (const int*)d_in[1];
    const float* W     = (const float*)d_in[2];
    const float* bias  = (const float*)d_in[3];
    float* out = (float*)d_out;

    const size_t h_bytes  = (size_t)NNODES * DOUT * sizeof(unsigned short); // 25.6 MB
    const size_t wt_bytes = (size_t)DIN * DOUT * sizeof(unsigned short);    // 64 KB

    unsigned short* h = (unsigned short*)d_ws;
    unsigned short* Wt;
    if (ws_size >= h_bytes + wt_bytes)
        Wt = (unsigned short*)((char*)d_ws + h_bytes);
    else
        Wt = (unsigned short*)d_out;   // gather fully overwrites d_out later

    gc_wt<<<(DIN * DOUT) / 256, 256, 0, stream>>>(W, Wt);

    const int gemm_blocks = (NNODES + 63) / 64;     // 1563
    gc_linear_relu<<<gemm_blocks, 256, 0, stream>>>(feats, Wt, bias, h);

    const int gat_blocks = (NNODES + 15) / 16;      // 6250
    gc_gather_mean<<<gat_blocks, 256, 0, stream>>>(edge, h, out);
}